// Round 11
// baseline (104.396 us; speedup 1.0000x reference)
//
#include <hip/hip_runtime.h>

// B=2, HEADS=8, T=8, QH=QW=16, D=64; rows = 32768, K = 2048.
// out[row, k] = scores[row, k] + dotH(qh,kh) + dotW(qw,kw) + dotT(t,kt)
// k = kt*256 + kh*16 + kw; row = (b*H+n)*2048 + t*256 + qh*16 + qw.
//
// v11: v10 with 2 rows per wave (4096 blocks x 4 waves). All 16 stream
// loads issued first (2x MLP per wave, halved per-wave fixed costs), both
// coalesced-butterfly preludes run under them, then both add+nt-store
// bursts. launch_bounds(256,4): 16 v4f stream buffers need ~110 VGPRs.

#define WAVES 4
#define RPW   2

typedef float v4f __attribute__((ext_vector_type(4)));

__global__ __launch_bounds__(256, 4) void relpos_fused_v11(
    const float* __restrict__ query,   // [32768, 64]
    const float* __restrict__ scores,  // [32768, 2048]
    const float* __restrict__ hemb,    // [31, 64]
    const float* __restrict__ wemb,    // [31, 64]
    const float* __restrict__ temb,    // [15, 64]
    float* __restrict__ out)           // [32768, 2048]
{
    __shared__ __align__(16) float bias_all[WAVES * RPW][48];

    const int tid  = threadIdx.x;
    const int wv   = tid >> 6;             // wave id
    const int lane = tid & 63;

    const int rbase = (blockIdx.x * WAVES + wv) * RPW;  // first row of wave

    // --- Issue ALL 16 stream loads first; pin ahead of preludes ---
    const v4f* s4pA = (const v4f*)scores + (size_t)rbase * 512 + lane;
    const v4f* s4pB = s4pA + 512;
    v4f*       o4pA = (v4f*)out          + (size_t)rbase * 512 + lane;
    v4f*       o4pB = o4pA + 512;

    v4f sA[8], sB[8];
    #pragma unroll
    for (int k = 0; k < 8; ++k)
        sA[k] = __builtin_nontemporal_load(&s4pA[k * 64]);
    #pragma unroll
    for (int k = 0; k < 8; ++k)
        sB[k] = __builtin_nontemporal_load(&s4pB[k * 64]);
    __builtin_amdgcn_sched_barrier(0);

    // --- Preludes for both rows (coalesced butterfly, 40 dots each) ---
    const int g = lane >> 4;   // group 0..3
    const int i = lane & 15;   // position within group

    #pragma unroll
    for (int r = 0; r < RPW; ++r) {
        const int grow = rbase + r;
        const int row  = grow & 2047;
        const int tt   = row >> 8;
        const int qh   = (row >> 4) & 15;
        const int qw   = row & 15;
        const v4f q4 = ((const v4f*)(query + (size_t)grow * 64))[i];
        #pragma unroll
        for (int j = 0; j < 10; ++j) {
            const int d = g * 10 + j;      // dot index 0..39
            const float* erow;
            if (d < 16)      erow = hemb + (qh - d + 15) * 64;
            else if (d < 32) erow = wemb + (qw - (d - 16) + 15) * 64;
            else             erow = temb + (tt - (d - 32) + 7) * 64;
            const v4f e4 = ((const v4f*)erow)[i];
            const v4f p4 = q4 * e4;
            float p = (p4.x + p4.y) + (p4.z + p4.w);
            p += __shfl_xor(p, 1, 64);
            p += __shfl_xor(p, 2, 64);
            p += __shfl_xor(p, 4, 64);
            p += __shfl_xor(p, 8, 64);
            if (i == 0) bias_all[wv * RPW + r][d] = p;
        }
    }
    // Own-wave LDS write->read: no barrier needed.

    // element = i*256 + lane*4 + c  =>  kt=i, kh=lane>>2, kw quad = lane&3
    const float* bA = bias_all[wv * RPW + 0];
    const float* bB = bias_all[wv * RPW + 1];
    const v4f hwA = *(const v4f*)(bA + 16 + (lane & 3) * 4) + bA[lane >> 2];
    const v4f hwB = *(const v4f*)(bB + 16 + (lane & 3) * 4) + bB[lane >> 2];

    // --- Add + nt store, row A then row B ---
    #pragma unroll
    for (int k = 0; k < 8; ++k) {
        v4f o = sA[k] + hwA + bA[32 + k];
        __builtin_nontemporal_store(o, &o4pA[k * 64]);
    }
    #pragma unroll
    for (int k = 0; k < 8; ++k) {
        v4f o = sB[k] + hwB + bB[32 + k];
        __builtin_nontemporal_store(o, &o4pB[k * 64]);
    }
}

extern "C" void kernel_launch(void* const* d_in, const int* in_sizes, int n_in,
                              void* d_out, int out_size, void* d_ws, size_t ws_size,
                              hipStream_t stream) {
    const float* query  = (const float*)d_in[0];
    const float* scores = (const float*)d_in[1];
    const float* hemb   = (const float*)d_in[2];
    const float* wemb   = (const float*)d_in[3];
    const float* temb   = (const float*)d_in[4];
    float* out = (float*)d_out;

    relpos_fused_v11<<<32768 / (WAVES * RPW), 256, 0, stream>>>(
        query, scores, hemb, wemb, temb, out);
}